// Round 1
// baseline (400.719 us; speedup 1.0000x reference)
//
#include <hip/hip_runtime.h>
#include <hip/hip_bf16.h>
#include <hip/hip_fp16.h>

#define DIM 512
#define HID 2048
#define NE 8
#define NTOK 4096

typedef _Float16 v8h __attribute__((ext_vector_type(8)));
typedef _Float16 v4h __attribute__((ext_vector_type(4)));
typedef float v4f __attribute__((ext_vector_type(4)));

__device__ __forceinline__ void load16(const void* g, void* l) {
  __builtin_amdgcn_global_load_lds(
      (const __attribute__((address_space(1))) unsigned int*)g,
      (__attribute__((address_space(3))) unsigned int*)l, 16, 0, 0);
}

// fast erf (Abramowitz-Stegun 7.1.26, abs err ~1.5e-7)
__device__ __forceinline__ float gelu_erf(float v) {
  float z = v * 0.70710678118654752f;
  float az = __builtin_fabsf(z);
  float t = __builtin_amdgcn_rcpf(1.0f + 0.3275911f * az);
  float poly = 1.061405429f;
  poly = poly * t - 1.453152027f;
  poly = poly * t + 1.421413741f;
  poly = poly * t - 0.284496736f;
  poly = poly * t + 0.254829592f;
  poly = poly * t;
  float erf_abs = 1.0f - poly * __expf(-z * z);
  float erf = __builtin_copysignf(erf_abs, z);
  return 0.5f * v * (1.0f + erf);
}

__global__ __launch_bounds__(256) void convert_x_kernel(const float* __restrict__ x,
                                                        _Float16* __restrict__ xh) {
  size_t i = ((size_t)blockIdx.x * 256 + threadIdx.x) * 8;
  const float4* xv = (const float4*)(x + i);
  float4 a = xv[0], b = xv[1];
  v8h o;
  o[0] = (_Float16)a.x; o[1] = (_Float16)a.y; o[2] = (_Float16)a.z; o[3] = (_Float16)a.w;
  o[4] = (_Float16)b.x; o[5] = (_Float16)b.y; o[6] = (_Float16)b.z; o[7] = (_Float16)b.w;
  *(v8h*)(xh + i) = o;
}

// in: fp32 [E][R][C]  ->  out: f16 [E][C][R]
__global__ __launch_bounds__(256) void transpose_cvt_kernel(const float* __restrict__ in,
                                                            _Float16* __restrict__ outp,
                                                            int R, int C, int tiles_r,
                                                            int blocks_per_e) {
  const int bx = blockIdx.x;
  const int e = bx / blocks_per_e;
  const int rem = bx - e * blocks_per_e;
  const int rt = rem % tiles_r;
  const int ct = rem / tiles_r;
  const int r0 = rt << 5, c0 = ct << 5;
  __shared__ float tile[32][33];
  const int tr = threadIdx.x >> 3;          // 0..31
  const int tc = (threadIdx.x & 7) << 2;    // 0,4,..,28
  const float4 v = *(const float4*)(in + (size_t)e * R * C + (size_t)(r0 + tr) * C + c0 + tc);
  tile[tc + 0][tr] = v.x;
  tile[tc + 1][tr] = v.y;
  tile[tc + 2][tr] = v.z;
  tile[tc + 3][tr] = v.w;
  __syncthreads();
  v4h h;
  h[0] = (_Float16)tile[tr][tc + 0];
  h[1] = (_Float16)tile[tr][tc + 1];
  h[2] = (_Float16)tile[tr][tc + 2];
  h[3] = (_Float16)tile[tr][tc + 3];
  *(v4h*)(outp + (size_t)e * R * C + (size_t)(c0 + tr) * R + r0 + tc) = h;
}

__global__ __launch_bounds__(256) void routing_kernel(const float* __restrict__ x,
                                                      const float* __restrict__ rw,
                                                      const float* __restrict__ rb,
                                                      float* __restrict__ leaf) {
  const int lane = threadIdx.x & 63;
  const int wave = threadIdx.x >> 6;
  const int n = (blockIdx.x << 2) + wave;
  const float4* xv = (const float4*)(x + (size_t)n * DIM);
  const float4 x0 = xv[lane * 2], x1 = xv[lane * 2 + 1];
  float logits[7];
#pragma unroll
  for (int rr = 0; rr < 7; ++rr) {
    const float4* wv = (const float4*)(rw + rr * DIM);
    const float4 w0 = wv[lane * 2], w1v = wv[lane * 2 + 1];
    float s = x0.x * w0.x + x0.y * w0.y + x0.z * w0.z + x0.w * w0.w +
              x1.x * w1v.x + x1.y * w1v.y + x1.z * w1v.z + x1.w * w1v.w;
#pragma unroll
    for (int o = 32; o; o >>= 1) s += __shfl_xor(s, o, 64);
    logits[rr] = s + rb[rr];
  }
  if (lane < NE) {
    const int eidx = lane;
    const float p0 = 1.f / (1.f + __expf(-logits[0]));
    float f = ((eidx >> 2) & 1) ? p0 : 1.f - p0;
    const float p1 = 1.f / (1.f + __expf(-logits[1 + (eidx >> 2)]));
    f *= ((eidx >> 1) & 1) ? p1 : 1.f - p1;
    const float p2 = 1.f / (1.f + __expf(-logits[3 + (eidx >> 1)]));
    f *= (eidx & 1) ? p2 : 1.f - p2;
    leaf[(size_t)n * NE + eidx] = f;
  }
}

// H[e_local] = gelu(X @ W1[e]^T... (w1t is [E][HID][DIM], K-contiguous) + b1[e])
__global__ __launch_bounds__(256) void gemm1_kernel(const _Float16* __restrict__ xh,
                                                    const _Float16* __restrict__ w1t,
                                                    const float* __restrict__ b1,
                                                    _Float16* __restrict__ H,
                                                    int e_base, int ecnt) {
  const int bx = blockIdx.x;
  const int e_local = bx % ecnt;      // consecutive blocks -> different XCDs -> expert/XCD affinity
  const int t = bx / ecnt;
  const int mt = t & 31;
  const int nt = t >> 5;              // 0..15
  const int e = e_base + e_local;
  const int m0 = mt << 7, n0 = nt << 7;

  __shared__ alignas(16) _Float16 As[128 * 64];
  __shared__ alignas(16) _Float16 Bs[128 * 64];

  const int tid = threadIdx.x;
  const int lane = tid & 63;
  const int wave = tid >> 6;
  const int qm = wave >> 1, qn = wave & 1;
  const int r = lane & 15, q = lane >> 4;

  const _Float16* Ab = xh + (size_t)m0 * DIM;
  const _Float16* Bb = w1t + ((size_t)e * HID + n0) * DIM;

  v4f acc[4][4];
#pragma unroll
  for (int i = 0; i < 4; ++i)
#pragma unroll
    for (int j = 0; j < 4; ++j) acc[i][j] = v4f{0.f, 0.f, 0.f, 0.f};

  const int ch0 = wave << 8;
  for (int k0 = 0; k0 < DIM; k0 += 64) {
#pragma unroll
    for (int i = 0; i < 4; ++i) {
      const int ch = ch0 + (i << 6) + lane;
      const int row = ch >> 3, c8 = ch & 7;
      load16(Ab + (size_t)row * DIM + k0 + (c8 << 3), As + (size_t)ch * 8);
      load16(Bb + (size_t)row * DIM + k0 + (c8 << 3), Bs + (size_t)ch * 8);
    }
    __syncthreads();
#pragma unroll
    for (int ks = 0; ks < 64; ks += 32) {
      v8h a[4], b[4];
#pragma unroll
      for (int i = 0; i < 4; ++i)
        a[i] = *(const v8h*)(As + ((qm << 6) + (i << 4) + r) * 64 + ks + (q << 3));
#pragma unroll
      for (int j = 0; j < 4; ++j)
        b[j] = *(const v8h*)(Bs + ((qn << 6) + (j << 4) + r) * 64 + ks + (q << 3));
#pragma unroll
      for (int i = 0; i < 4; ++i)
#pragma unroll
        for (int j = 0; j < 4; ++j)
          acc[i][j] = __builtin_amdgcn_mfma_f32_16x16x32_f16(a[i], b[j], acc[i][j], 0, 0, 0);
    }
    __syncthreads();
  }

  const float* b1e = b1 + (size_t)e * HID;
  _Float16* He = H + (size_t)e_local * NTOK * HID;
#pragma unroll
  for (int j = 0; j < 4; ++j) {
    const int col = n0 + (qn << 6) + (j << 4) + r;
    const float bias = b1e[col];
#pragma unroll
    for (int i = 0; i < 4; ++i) {
      const int rowb = m0 + (qm << 6) + (i << 4) + (q << 2);
#pragma unroll
      for (int rr = 0; rr < 4; ++rr) {
        float v = acc[i][j][rr] + bias;
        He[(size_t)(rowb + rr) * HID + col] = (_Float16)gelu_erf(v);
      }
    }
  }
}

// out += leaf[:,e] * (H[e_local] @ W2[e]... (w2t is [E][DIM][HID], K-contiguous) + b2[e])
__global__ __launch_bounds__(256) void gemm2_kernel(const _Float16* __restrict__ H,
                                                    const _Float16* __restrict__ w2t,
                                                    const float* __restrict__ b2,
                                                    const float* __restrict__ leaf,
                                                    float* __restrict__ out,
                                                    int e_base, int ecnt) {
  const int bx = blockIdx.x;
  const int e_local = bx % ecnt;
  const int t = bx / ecnt;
  const int mt = t & 31;
  const int dt = t >> 5;              // 0..3
  const int e = e_base + e_local;
  const int m0 = mt << 7, d0 = dt << 7;

  __shared__ alignas(16) _Float16 As[128 * 64];
  __shared__ alignas(16) _Float16 Bs[128 * 64];

  const int tid = threadIdx.x;
  const int lane = tid & 63;
  const int wave = tid >> 6;
  const int qm = wave >> 1, qn = wave & 1;
  const int r = lane & 15, q = lane >> 4;

  const _Float16* Ab = H + ((size_t)e_local * NTOK + m0) * HID;
  const _Float16* Bb = w2t + ((size_t)e * DIM + d0) * HID;

  v4f acc[4][4];
#pragma unroll
  for (int i = 0; i < 4; ++i)
#pragma unroll
    for (int j = 0; j < 4; ++j) acc[i][j] = v4f{0.f, 0.f, 0.f, 0.f};

  const int ch0 = wave << 8;
  for (int k0 = 0; k0 < HID; k0 += 64) {
#pragma unroll
    for (int i = 0; i < 4; ++i) {
      const int ch = ch0 + (i << 6) + lane;
      const int row = ch >> 3, c8 = ch & 7;
      load16(Ab + (size_t)row * HID + k0 + (c8 << 3), As + (size_t)ch * 8);
      load16(Bb + (size_t)row * HID + k0 + (c8 << 3), Bs + (size_t)ch * 8);
    }
    __syncthreads();
#pragma unroll
    for (int ks = 0; ks < 64; ks += 32) {
      v8h a[4], b[4];
#pragma unroll
      for (int i = 0; i < 4; ++i)
        a[i] = *(const v8h*)(As + ((qm << 6) + (i << 4) + r) * 64 + ks + (q << 3));
#pragma unroll
      for (int j = 0; j < 4; ++j)
        b[j] = *(const v8h*)(Bs + ((qn << 6) + (j << 4) + r) * 64 + ks + (q << 3));
#pragma unroll
      for (int i = 0; i < 4; ++i)
#pragma unroll
        for (int j = 0; j < 4; ++j)
          acc[i][j] = __builtin_amdgcn_mfma_f32_16x16x32_f16(a[i], b[j], acc[i][j], 0, 0, 0);
    }
    __syncthreads();
  }

  const float* b2e = b2 + (size_t)e * DIM;
#pragma unroll
  for (int i = 0; i < 4; ++i) {
    const int rowb = m0 + (qm << 6) + (i << 4) + (q << 2);
    float p[4];
#pragma unroll
    for (int rr = 0; rr < 4; ++rr) p[rr] = leaf[(size_t)(rowb + rr) * NE + e];
#pragma unroll
    for (int j = 0; j < 4; ++j) {
      const int col = d0 + (qn << 6) + (j << 4) + r;
      const float bias = b2e[col];
#pragma unroll
      for (int rr = 0; rr < 4; ++rr) {
        atomicAdd(out + (size_t)(rowb + rr) * DIM + col, p[rr] * (acc[i][j][rr] + bias));
      }
    }
  }
}

extern "C" void kernel_launch(void* const* d_in, const int* in_sizes, int n_in,
                              void* d_out, int out_size, void* d_ws, size_t ws_size,
                              hipStream_t stream) {
  const float* x  = (const float*)d_in[0];
  const float* rw = (const float*)d_in[1];
  const float* rb = (const float*)d_in[2];
  const float* w1 = (const float*)d_in[3];
  const float* b1 = (const float*)d_in[4];
  const float* w2 = (const float*)d_in[5];
  const float* b2 = (const float*)d_in[6];
  float* out = (float*)d_out;

  char* ws = (char*)d_ws;
  const size_t xh_bytes  = (size_t)NTOK * DIM * 2;        // 4 MiB
  const size_t w1t_bytes = (size_t)NE * HID * DIM * 2;    // 16 MiB
  const size_t w2t_bytes = (size_t)NE * DIM * HID * 2;    // 16 MiB
  const size_t leaf_bytes = (size_t)NTOK * NE * 4;        // 128 KiB
  _Float16* xh   = (_Float16*)(ws);
  _Float16* w1t  = (_Float16*)(ws + xh_bytes);
  _Float16* w2t  = (_Float16*)(ws + xh_bytes + w1t_bytes);
  float*    leaf = (float*)(ws + xh_bytes + w1t_bytes + w2t_bytes);
  _Float16* Hbuf = (_Float16*)(ws + xh_bytes + w1t_bytes + w2t_bytes + leaf_bytes);
  const size_t used = xh_bytes + w1t_bytes + w2t_bytes + leaf_bytes;
  const size_t Hper = (size_t)NTOK * HID * 2;             // 16 MiB per expert

  int EC = 1;
  if (ws_size >= used + 8 * Hper) EC = 8;
  else if (ws_size >= used + 4 * Hper) EC = 4;
  else if (ws_size >= used + 2 * Hper) EC = 2;
  if (ws_size < used + Hper) return;  // workspace too small; fail visibly

  hipMemsetAsync(d_out, 0, (size_t)out_size * sizeof(float), stream);
  convert_x_kernel<<<1024, 256, 0, stream>>>(x, xh);
  transpose_cvt_kernel<<<8192, 256, 0, stream>>>(w1, w1t, DIM, HID, DIM / 32, 1024);
  transpose_cvt_kernel<<<8192, 256, 0, stream>>>(w2, w2t, HID, DIM, HID / 32, 1024);
  routing_kernel<<<1024, 256, 0, stream>>>(x, rw, rb, leaf);
  for (int e0 = 0; e0 < NE; e0 += EC) {
    gemm1_kernel<<<EC * 512, 256, 0, stream>>>(xh, w1t, b1, Hbuf, e0, EC);
    gemm2_kernel<<<EC * 128, 256, 0, stream>>>(Hbuf, w2t, b2, leaf, out, e0, EC);
  }
}

// Round 2
// 339.978 us; speedup vs baseline: 1.1787x; 1.1787x over previous
//
#include <hip/hip_runtime.h>
#include <hip/hip_bf16.h>
#include <hip/hip_fp16.h>

#define DIM 512
#define HID 2048
#define NE 8
#define NTOK 4096

typedef _Float16 v8h __attribute__((ext_vector_type(8)));
typedef float v4f __attribute__((ext_vector_type(4)));

__device__ __forceinline__ void load16(const void* g, void* l) {
  __builtin_amdgcn_global_load_lds(
      (const __attribute__((address_space(1))) unsigned int*)g,
      (__attribute__((address_space(3))) unsigned int*)l, 16, 0, 0);
}

// fast erf-gelu (Abramowitz-Stegun 7.1.26, abs err ~1.5e-7)
__device__ __forceinline__ float gelu_erf(float v) {
  float z = v * 0.70710678118654752f;
  float az = __builtin_fabsf(z);
  float t = __builtin_amdgcn_rcpf(1.0f + 0.3275911f * az);
  float poly = 1.061405429f;
  poly = poly * t - 1.453152027f;
  poly = poly * t + 1.421413741f;
  poly = poly * t - 0.284496736f;
  poly = poly * t + 0.254829592f;
  poly = poly * t;
  float erf_abs = 1.0f - poly * __expf(-z * z);
  float erf = __builtin_copysignf(erf_abs, z);
  return 0.5f * v * (1.0f + erf);
}

// routing + x->f16 conversion fused: one wave per token
__global__ __launch_bounds__(256) void routing_kernel(const float* __restrict__ x,
                                                      const float* __restrict__ rw,
                                                      const float* __restrict__ rb,
                                                      float* __restrict__ leaf,
                                                      _Float16* __restrict__ xh) {
  const int lane = threadIdx.x & 63;
  const int wave = threadIdx.x >> 6;
  const int n = (blockIdx.x << 2) + wave;
  const float4* xv = (const float4*)(x + (size_t)n * DIM);
  const float4 x0 = xv[lane * 2], x1 = xv[lane * 2 + 1];
  // each lane holds x[n][lane*8 .. lane*8+7] -> free f16 conversion
  v8h o;
  o[0] = (_Float16)x0.x; o[1] = (_Float16)x0.y; o[2] = (_Float16)x0.z; o[3] = (_Float16)x0.w;
  o[4] = (_Float16)x1.x; o[5] = (_Float16)x1.y; o[6] = (_Float16)x1.z; o[7] = (_Float16)x1.w;
  *(v8h*)(xh + (size_t)n * DIM + lane * 8) = o;
  float logits[7];
#pragma unroll
  for (int rr = 0; rr < 7; ++rr) {
    const float4* wv = (const float4*)(rw + rr * DIM);
    const float4 w0 = wv[lane * 2], w1v = wv[lane * 2 + 1];
    float s = x0.x * w0.x + x0.y * w0.y + x0.z * w0.z + x0.w * w0.w +
              x1.x * w1v.x + x1.y * w1v.y + x1.z * w1v.z + x1.w * w1v.w;
#pragma unroll
    for (int o2 = 32; o2; o2 >>= 1) s += __shfl_xor(s, o2, 64);
    logits[rr] = s + rb[rr];
  }
  if (lane < NE) {
    const int eidx = lane;
    const float p0 = 1.f / (1.f + __expf(-logits[0]));
    float f = ((eidx >> 2) & 1) ? p0 : 1.f - p0;
    const float p1 = 1.f / (1.f + __expf(-logits[1 + (eidx >> 2)]));
    f *= ((eidx >> 1) & 1) ? p1 : 1.f - p1;
    const float p2 = 1.f / (1.f + __expf(-logits[3 + (eidx >> 1)]));
    f *= (eidx & 1) ? p2 : 1.f - p2;
    leaf[(size_t)n * NE + eidx] = f;
  }
}

// both weight transposes in one launch. in fp32 [E][R][C] -> out f16 [E][C][R]
// tile: 64 in-rows x 32 in-cols -> out writes are 128B-contiguous per out-row.
__global__ __launch_bounds__(256) void transpose_cvt2_kernel(const float* __restrict__ w1,
                                                             _Float16* __restrict__ w1t,
                                                             const float* __restrict__ w2,
                                                             _Float16* __restrict__ w2t) {
  int bx = blockIdx.x;
  const float* in;
  _Float16* outp;
  int R, C;
  if (bx < 4096) { in = w1; outp = w1t; R = DIM; C = HID; }
  else { bx -= 4096; in = w2; outp = w2t; R = HID; C = DIM; }
  const int e = bx >> 9;
  const int rem = bx & 511;
  const int tiles_r = R >> 6;
  const int rt = rem % tiles_r;
  const int ct = rem / tiles_r;
  const int r0 = rt << 6, c0 = ct << 5;
  const size_t ebase = (size_t)e * R * C;

  __shared__ float tile[32][65];  // [col][row], pad 65 -> conflict-free both phases
  const int tid = threadIdx.x;
#pragma unroll
  for (int it = 0; it < 2; ++it) {
    const int s = tid + (it << 8);
    const int row = s >> 3, cq = s & 7;
    const float4 v = *(const float4*)(in + ebase + (size_t)(r0 + row) * C + c0 + (cq << 2));
    tile[(cq << 2) + 0][row] = v.x;
    tile[(cq << 2) + 1][row] = v.y;
    tile[(cq << 2) + 2][row] = v.z;
    tile[(cq << 2) + 3][row] = v.w;
  }
  __syncthreads();
  const int c = tid >> 3, seg = tid & 7;
  v8h h;
#pragma unroll
  for (int u = 0; u < 8; ++u) h[u] = (_Float16)tile[c][(seg << 3) + u];
  *(v8h*)(outp + ebase + (size_t)(c0 + c) * R + r0 + (seg << 3)) = h;
}

// out[n,d] = sum_e leaf[n,e]*b2[e,d]   (replaces memset; bias-2 fold)
__global__ __launch_bounds__(256) void out_init_kernel(const float* __restrict__ leaf,
                                                       const float* __restrict__ b2,
                                                       float* __restrict__ out) {
  const int g = blockIdx.x * 256 + threadIdx.x;
  const int n = g >> 7, dq = g & 127;
  const float* lp = leaf + (size_t)n * NE;
  float4 acc = {0.f, 0.f, 0.f, 0.f};
#pragma unroll
  for (int e = 0; e < NE; ++e) {
    const float pe = lp[e];
    const float4 bv = *(const float4*)(b2 + (size_t)e * DIM + (dq << 2));
    acc.x += pe * bv.x; acc.y += pe * bv.y; acc.z += pe * bv.z; acc.w += pe * bv.w;
  }
  *(float4*)(out + (size_t)n * DIM + (dq << 2)) = acc;
}

// H'[e][n][h] = leaf[n,e] * gelu(X @ W1[e]^T + b1[e])   (p folded in)
__global__ __launch_bounds__(256) void gemm1_kernel(const _Float16* __restrict__ xh,
                                                    const _Float16* __restrict__ w1t,
                                                    const float* __restrict__ b1,
                                                    const float* __restrict__ leaf,
                                                    _Float16* __restrict__ H) {
  const int bx = blockIdx.x;
  const int e = bx & 7;                 // expert == XCD (bx%8): W1t[e] L2-resident
  const int t = bx >> 3;
  const int mt = t & 31;
  const int nt = t >> 5;                // 0..15
  const int m0 = mt << 7, n0 = nt << 7;

  __shared__ alignas(16) _Float16 As[128 * 64];
  __shared__ alignas(16) _Float16 Bs[128 * 64];

  const int tid = threadIdx.x;
  const int lane = tid & 63;
  const int wave = tid >> 6;
  const int qm = wave >> 1, qn = wave & 1;
  const int r = lane & 15, q = lane >> 4;

  const _Float16* Ab = xh + (size_t)m0 * DIM;
  const _Float16* Bb = w1t + ((size_t)e * HID + n0) * DIM;

  v4f acc[4][4];
#pragma unroll
  for (int i = 0; i < 4; ++i)
#pragma unroll
    for (int j = 0; j < 4; ++j) acc[i][j] = v4f{0.f, 0.f, 0.f, 0.f};

  const int ch0 = wave << 8;
  for (int k0 = 0; k0 < DIM; k0 += 64) {
#pragma unroll
    for (int i = 0; i < 4; ++i) {
      const int ch = ch0 + (i << 6) + lane;
      const int row = ch >> 3;
      const int c8 = (ch & 7) ^ (row & 7);   // XOR-swizzled column slot
      load16(Ab + (size_t)row * DIM + k0 + (c8 << 3), As + (size_t)ch * 8);
      load16(Bb + (size_t)row * DIM + k0 + (c8 << 3), Bs + (size_t)ch * 8);
    }
    __syncthreads();
#pragma unroll
    for (int ks = 0; ks < 64; ks += 32) {
      v8h a[4], b[4];
#pragma unroll
      for (int i = 0; i < 4; ++i) {
        const int row = (qm << 6) + (i << 4) + r;
        const int s = (((ks >> 3) + q) ^ (row & 7));
        a[i] = *(const v8h*)(As + (row << 6) + (s << 3));
      }
#pragma unroll
      for (int j = 0; j < 4; ++j) {
        const int row = (qn << 6) + (j << 4) + r;
        const int s = (((ks >> 3) + q) ^ (row & 7));
        b[j] = *(const v8h*)(Bs + (row << 6) + (s << 3));
      }
#pragma unroll
      for (int i = 0; i < 4; ++i)
#pragma unroll
        for (int j = 0; j < 4; ++j)
          acc[i][j] = __builtin_amdgcn_mfma_f32_16x16x32_f16(a[i], b[j], acc[i][j], 0, 0, 0);
    }
    __syncthreads();
  }

  const float* b1e = b1 + (size_t)e * HID;
  _Float16* He = H + (size_t)e * NTOK * HID;
  float bias[4];
#pragma unroll
  for (int j = 0; j < 4; ++j) bias[j] = b1e[n0 + (qn << 6) + (j << 4) + r];
#pragma unroll
  for (int i = 0; i < 4; ++i) {
    const int rowb = m0 + (qm << 6) + (i << 4) + (q << 2);
#pragma unroll
    for (int rr = 0; rr < 4; ++rr) {
      const int row = rowb + rr;
      const float p = leaf[(size_t)row * NE + e];
#pragma unroll
      for (int j = 0; j < 4; ++j) {
        const int col = n0 + (qn << 6) + (j << 4) + r;
        He[(size_t)row * HID + col] = (_Float16)(p * gelu_erf(acc[i][j][rr] + bias[j]));
      }
    }
  }
}

// out += H'[4096,16384] @ W2cat[16384,512], split-K=4 (k-tiles never cross experts)
__global__ __launch_bounds__(256) void gemm2_kernel(const _Float16* __restrict__ H,
                                                    const _Float16* __restrict__ w2t,
                                                    float* __restrict__ out) {
  const int bx = blockIdx.x;
  const int mt = bx & 31;               // bx%8 == mt%8: all d-tiles of an m-tile share an XCD
  const int dt = (bx >> 5) & 3;
  const int sp = bx >> 7;               // 0..3
  const int m0 = mt << 7, d0 = dt << 7;
  const int kbase = sp << 12;           // 4096 K per split

  __shared__ alignas(16) _Float16 As[128 * 64];
  __shared__ alignas(16) _Float16 Bs[128 * 64];

  const int tid = threadIdx.x;
  const int lane = tid & 63;
  const int wave = tid >> 6;
  const int qm = wave >> 1, qn = wave & 1;
  const int r = lane & 15, q = lane >> 4;

  v4f acc[4][4];
#pragma unroll
  for (int i = 0; i < 4; ++i)
#pragma unroll
    for (int j = 0; j < 4; ++j) acc[i][j] = v4f{0.f, 0.f, 0.f, 0.f};

  const int ch0 = wave << 8;
  for (int kk = 0; kk < 4096; kk += 64) {
    const int kg = kbase + kk;
    const int e = kg >> 11;             // expert of this k-tile
    const int kl = kg & 2047;
    const _Float16* Ab = H + ((size_t)e * NTOK + m0) * HID + kl;
    const _Float16* Bb = w2t + ((size_t)e * DIM + d0) * HID + kl;
#pragma unroll
    for (int i = 0; i < 4; ++i) {
      const int ch = ch0 + (i << 6) + lane;
      const int row = ch >> 3;
      const int c8 = (ch & 7) ^ (row & 7);
      load16(Ab + (size_t)row * HID + (c8 << 3), As + (size_t)ch * 8);
      load16(Bb + (size_t)row * HID + (c8 << 3), Bs + (size_t)ch * 8);
    }
    __syncthreads();
#pragma unroll
    for (int ks = 0; ks < 64; ks += 32) {
      v8h a[4], b[4];
#pragma unroll
      for (int i = 0; i < 4; ++i) {
        const int row = (qm << 6) + (i << 4) + r;
        const int s = (((ks >> 3) + q) ^ (row & 7));
        a[i] = *(const v8h*)(As + (row << 6) + (s << 3));
      }
#pragma unroll
      for (int j = 0; j < 4; ++j) {
        const int row = (qn << 6) + (j << 4) + r;
        const int s = (((ks >> 3) + q) ^ (row & 7));
        b[j] = *(const v8h*)(Bs + (row << 6) + (s << 3));
      }
#pragma unroll
      for (int i = 0; i < 4; ++i)
#pragma unroll
        for (int j = 0; j < 4; ++j)
          acc[i][j] = __builtin_amdgcn_mfma_f32_16x16x32_f16(a[i], b[j], acc[i][j], 0, 0, 0);
    }
    __syncthreads();
  }

#pragma unroll
  for (int i = 0; i < 4; ++i) {
    const int rowb = m0 + (qm << 6) + (i << 4) + (q << 2);
#pragma unroll
    for (int j = 0; j < 4; ++j) {
      const int col = d0 + (qn << 6) + (j << 4) + r;
#pragma unroll
      for (int rr = 0; rr < 4; ++rr)
        atomicAdd(out + (size_t)(rowb + rr) * DIM + col, acc[i][j][rr]);
    }
  }
}

extern "C" void kernel_launch(void* const* d_in, const int* in_sizes, int n_in,
                              void* d_out, int out_size, void* d_ws, size_t ws_size,
                              hipStream_t stream) {
  const float* x  = (const float*)d_in[0];
  const float* rw = (const float*)d_in[1];
  const float* rb = (const float*)d_in[2];
  const float* w1 = (const float*)d_in[3];
  const float* b1 = (const float*)d_in[4];
  const float* w2 = (const float*)d_in[5];
  const float* b2 = (const float*)d_in[6];
  float* out = (float*)d_out;

  char* ws = (char*)d_ws;
  const size_t xh_bytes   = (size_t)NTOK * DIM * 2;       // 4 MiB
  const size_t w1t_bytes  = (size_t)NE * HID * DIM * 2;   // 16 MiB
  const size_t w2t_bytes  = (size_t)NE * DIM * HID * 2;   // 16 MiB
  const size_t leaf_bytes = (size_t)NTOK * NE * 4;        // 128 KiB
  const size_t H_bytes    = (size_t)NE * NTOK * HID * 2;  // 128 MiB
  _Float16* xh   = (_Float16*)(ws);
  _Float16* w1t  = (_Float16*)(ws + xh_bytes);
  _Float16* w2t  = (_Float16*)(ws + xh_bytes + w1t_bytes);
  float*    leaf = (float*)(ws + xh_bytes + w1t_bytes + w2t_bytes);
  _Float16* Hbuf = (_Float16*)(ws + xh_bytes + w1t_bytes + w2t_bytes + leaf_bytes);
  if (ws_size < xh_bytes + w1t_bytes + w2t_bytes + leaf_bytes + H_bytes) return;

  routing_kernel<<<1024, 256, 0, stream>>>(x, rw, rb, leaf, xh);
  transpose_cvt2_kernel<<<8192, 256, 0, stream>>>(w1, w1t, w2, w2t);
  out_init_kernel<<<2048, 256, 0, stream>>>(leaf, b2, out);
  gemm1_kernel<<<4096, 256, 0, stream>>>(xh, w1t, b1, leaf, Hbuf);
  gemm2_kernel<<<512, 256, 0, stream>>>(Hbuf, w2t, out);
}